// Round 1
// baseline (673.767 us; speedup 1.0000x reference)
//
#include <hip/hip_runtime.h>
#include <hip/hip_bf16.h>
#include <stdint.h>

// Problem: B=2, S=2048, D=2048, H=16, HD=128
#define S_ 2048
#define D_ 2048
#define H_ 16
#define HD_ 128

typedef __bf16 bf16x8 __attribute__((ext_vector_type(8)));
typedef float f32x4 __attribute__((ext_vector_type(4)));
typedef unsigned short ushort_t;
typedef ushort_t us4 __attribute__((ext_vector_type(4)));

#define NEG_INF (-__builtin_inff())

__device__ __forceinline__ float bf2f(ushort_t u) {
  union { float f; uint32_t i; } x; x.i = ((uint32_t)u) << 16; return x.f;
}
__device__ __forceinline__ ushort_t f2bf(float f) {
  union { float f; uint32_t i; } x; x.f = f;
  uint32_t r = x.i + 0x7fffu + ((x.i >> 16) & 1u);  // RNE
  return (ushort_t)(r >> 16);
}

// async global->LDS, 16B per lane. LDS dest is wave-uniform base + lane*16.
__device__ __forceinline__ void async_copy16(const void* g, void* l) {
  __builtin_amdgcn_global_load_lds(
      (const __attribute__((address_space(1))) unsigned int*)g,
      (__attribute__((address_space(3))) unsigned int*)l, 16, 0, 0);
}

__device__ __forceinline__ void store_val(float* p, float v) { *p = v; }
__device__ __forceinline__ void store_val(ushort_t* p, float v) { *p = f2bf(v); }

// ---------------- fp32 -> bf16 convert (vectorized x4) ----------------
__global__ __launch_bounds__(256) void cvt_f32_bf16(const float* __restrict__ in,
                                                    ushort_t* __restrict__ out,
                                                    int n4) {
  int i = blockIdx.x * 256 + threadIdx.x;
  if (i >= n4) return;
  const float4 v = ((const float4*)in)[i];
  us4 o;
  o.x = f2bf(v.x); o.y = f2bf(v.y); o.z = f2bf(v.z); o.w = f2bf(v.w);
  ((us4*)out)[i] = o;
}

// ---------------- GEMM: C[M,N] = A[M,K] * B[N,K]^T  (both bf16, fp32 acc) ----
// m97 structure: 128x128 tile, BK=32, 4 waves in 2x2, global_load_lds width=16.
template <typename OutT>
__global__ __launch_bounds__(256) void gemm_bt(const ushort_t* __restrict__ A,
                                               const ushort_t* __restrict__ Bm,
                                               OutT* __restrict__ C,
                                               int M, int N, int K) {
  __shared__ __align__(16) ushort_t As[128 * 32];
  __shared__ __align__(16) ushort_t Bs[128 * 32];
  const int tid = threadIdx.x;
  const int wave = tid >> 6, lane = tid & 63;
  const int quad = lane >> 4, l16 = lane & 15;
  const int bm = blockIdx.y * 128, bn = blockIdx.x * 128;
  const int wm = (wave >> 1) * 64, wn = (wave & 1) * 64;

  f32x4 acc[4][4] = {};

  // staging: chunk c covers rows [c*16, c*16+16); lane -> (row=lane>>2, col8=(lane&3)*8)
  const int c0 = wave * 2, c1 = c0 + 1;
  const int srow = lane >> 2;
  const int scol = (lane & 3) * 8;
  const ushort_t* gA0 = A + (size_t)(bm + c0 * 16 + srow) * K + scol;
  const ushort_t* gA1 = A + (size_t)(bm + c1 * 16 + srow) * K + scol;
  const ushort_t* gB0 = Bm + (size_t)(bn + c0 * 16 + srow) * K + scol;
  const ushort_t* gB1 = Bm + (size_t)(bn + c1 * 16 + srow) * K + scol;
  ushort_t* lA0 = As + c0 * 512;
  ushort_t* lA1 = As + c1 * 512;
  ushort_t* lB0 = Bs + c0 * 512;
  ushort_t* lB1 = Bs + c1 * 512;

  for (int k0 = 0; k0 < K; k0 += 32) {
    __syncthreads();  // previous compute done before LDS overwrite
    async_copy16(gA0 + k0, lA0);
    async_copy16(gA1 + k0, lA1);
    async_copy16(gB0 + k0, lB0);
    async_copy16(gB1 + k0, lB1);
    __syncthreads();  // compiler drains vmcnt before barrier
    bf16x8 af[4], bfr[4];
#pragma unroll
    for (int i = 0; i < 4; ++i)
      af[i] = *(const bf16x8*)(As + (wm + i * 16 + l16) * 32 + quad * 8);
#pragma unroll
    for (int i = 0; i < 4; ++i)
      bfr[i] = *(const bf16x8*)(Bs + (wn + i * 16 + l16) * 32 + quad * 8);
#pragma unroll
    for (int mi = 0; mi < 4; ++mi)
#pragma unroll
      for (int ni = 0; ni < 4; ++ni)
        acc[mi][ni] = __builtin_amdgcn_mfma_f32_16x16x32_bf16(af[mi], bfr[ni],
                                                              acc[mi][ni], 0, 0, 0);
  }
  // epilogue: C/D layout col=lane&15, row=quad*4+reg
#pragma unroll
  for (int mi = 0; mi < 4; ++mi)
#pragma unroll
    for (int ni = 0; ni < 4; ++ni)
#pragma unroll
      for (int r = 0; r < 4; ++r) {
        int row = bm + wm + mi * 16 + quad * 4 + r;
        int col = bn + wn + ni * 16 + l16;
        store_val(&C[(size_t)row * N + col], acc[mi][ni][r]);
      }
}

// ---------------- RoPE in-place on q and k halves of qkv ----------------
// qkv layout: (B*S, 3*D) bf16; q cols [0,D), k cols [D,2D)
__global__ __launch_bounds__(256) void rope_k(ushort_t* __restrict__ qkv,
                                              const float* __restrict__ fc,
                                              const float* __restrict__ fs) {
  int idx = blockIdx.x * 256 + threadIdx.x;  // (m, h, i) = m*1024 + h*64 + i
  int i = idx & 63;
  int hh = (idx >> 6) & 15;
  int m = idx >> 10;
  int s = m & (S_ - 1);
  float c = fc[s * 64 + i], sn = fs[s * 64 + i];
  size_t off = (size_t)m * (3 * D_) + hh * HD_ + 2 * i;
#pragma unroll
  for (int part = 0; part < 2; ++part) {
    uint32_t* p = (uint32_t*)(qkv + off + part * D_);
    uint32_t v = *p;
    float re = bf2f((ushort_t)(v & 0xffffu));
    float im = bf2f((ushort_t)(v >> 16));
    float nr = re * c - im * sn;
    float ni = re * sn + im * c;
    *p = (uint32_t)f2bf(nr) | ((uint32_t)f2bf(ni) << 16);
  }
}

// ---------------- Flash attention (causal, online softmax) ----------------
// grid: (qt=S/64, H, B); block 256 (4 waves, 16 q-rows each)
__global__ __launch_bounds__(256) void attn_fwd(const ushort_t* __restrict__ qkv,
                                                ushort_t* __restrict__ attn_out) {
  const int qt = blockIdx.x, h = blockIdx.y, b = blockIdx.z;
  __shared__ __align__(16) ushort_t Kl[32 * 128];   // K tile, row=key
  __shared__ __align__(16) ushort_t VT[128 * 32];   // V tile transposed, row=d
  __shared__ __align__(16) ushort_t Pl[4 * 512];    // per-wave P scratch 16x32

  const int tid = threadIdx.x;
  const int wave = tid >> 6, lane = tid & 63;
  const int quad = lane >> 4, l16 = lane & 15;
  const float scale = 0.08838834764831845f;  // 1/sqrt(128)

  // Q fragments (A layout: m=lane&15, k=quad*8+j), rows fixed for the block
  const int qg = qt * 64 + wave * 16 + l16;
  const ushort_t* qrow = qkv + (size_t)(b * S_ + qg) * (3 * D_) + h * HD_;
  bf16x8 qf[4];
#pragma unroll
  for (int c = 0; c < 4; ++c)
    qf[c] = *(const bf16x8*)(qrow + c * 32 + quad * 8);

  f32x4 o[8] = {};
  float m_i[4], l_i[4];
#pragma unroll
  for (int r = 0; r < 4; ++r) { m_i[r] = NEG_INF; l_i[r] = 0.f; }

  const int q_row_base = qt * 64 + wave * 16 + quad * 4;  // C-layout rows
  const int nkt = qt * 2 + 2;  // causal: keys up to qt*64+63
  const int vr = tid & 31, vc = tid >> 5;
  ushort_t* Pw = Pl + wave * 512;

  for (int kt = 0; kt < nkt; ++kt) {
    __syncthreads();  // prior compute done before LDS overwrite
    // stage K tile (32 keys x 128) via async copy: 4 rows per wave-issue
#pragma unroll
    for (int i = 0; i < 2; ++i) {
      int rc = wave * 8 + i * 4;
      const ushort_t* g = qkv + (size_t)(b * S_ + kt * 32 + rc + quad) * (3 * D_) +
                          D_ + h * HD_ + l16 * 8;
      async_copy16(g, Kl + rc * 128);
    }
    // stage V tile transposed: thread loads 16 contiguous elems of one V row,
    // scatters to VT[d][key]
    {
      const ushort_t* vg = qkv + (size_t)(b * S_ + kt * 32 + vr) * (3 * D_) +
                           2 * D_ + h * HD_ + vc * 16;
      uint4 u0 = *(const uint4*)vg;
      uint4 u1 = *(const uint4*)(vg + 8);
      ushort_t tmp[16];
      *(uint4*)(tmp + 0) = u0;
      *(uint4*)(tmp + 8) = u1;
#pragma unroll
      for (int j = 0; j < 16; ++j) VT[(vc * 16 + j) * 32 + vr] = tmp[j];
    }
    __syncthreads();

    // QK^T for 2 key groups of 16 (K=128 over 4 MFMA each)
    float sv[2][4];
#pragma unroll
    for (int g2 = 0; g2 < 2; ++g2) {
      f32x4 s = {0.f, 0.f, 0.f, 0.f};
#pragma unroll
      for (int c = 0; c < 4; ++c) {
        bf16x8 kf = *(const bf16x8*)(Kl + (g2 * 16 + l16) * 128 + c * 32 + quad * 8);
        s = __builtin_amdgcn_mfma_f32_16x16x32_bf16(qf[c], kf, s, 0, 0, 0);
      }
      const int kcol = kt * 32 + g2 * 16 + l16;
#pragma unroll
      for (int r = 0; r < 4; ++r)
        sv[g2][r] = (kcol <= q_row_base + r) ? s[r] * scale : NEG_INF;
    }
    // online softmax per row (row = quad*4+r; 16 lanes of quad group hold cols)
#pragma unroll
    for (int r = 0; r < 4; ++r) {
      float mt = fmaxf(sv[0][r], sv[1][r]);
#pragma unroll
      for (int msk = 1; msk <= 8; msk <<= 1)
        mt = fmaxf(mt, __shfl_xor(mt, msk, 64));
      float nm = fmaxf(m_i[r], mt);
      float alpha = __expf(m_i[r] - nm);
      m_i[r] = nm;
      float p0 = __expf(sv[0][r] - nm);
      float p1 = __expf(sv[1][r] - nm);
      sv[0][r] = p0; sv[1][r] = p1;
      float ls = p0 + p1;
#pragma unroll
      for (int msk = 1; msk <= 8; msk <<= 1)
        ls += __shfl_xor(ls, msk, 64);
      l_i[r] = l_i[r] * alpha + ls;
#pragma unroll
      for (int dc = 0; dc < 8; ++dc) o[dc][r] *= alpha;
    }
    // P (C layout) -> LDS -> reload in A layout (verified m120 pattern)
#pragma unroll
    for (int g2 = 0; g2 < 2; ++g2)
#pragma unroll
      for (int r = 0; r < 4; ++r)
        Pw[(quad * 4 + r) * 32 + g2 * 16 + l16] = f2bf(sv[g2][r]);
    __syncthreads();
    bf16x8 pf = *(const bf16x8*)(Pw + l16 * 32 + quad * 8);
    // PV: K=32 (full key tile), 8 d-chunks
#pragma unroll
    for (int dc = 0; dc < 8; ++dc) {
      bf16x8 vf = *(const bf16x8*)(VT + (dc * 16 + l16) * 32 + quad * 8);
      o[dc] = __builtin_amdgcn_mfma_f32_16x16x32_bf16(pf, vf, o[dc], 0, 0, 0);
    }
  }
  // epilogue: divide by l, store bf16 to (B*S, D)
#pragma unroll
  for (int r = 0; r < 4; ++r) {
    float inv = 1.0f / l_i[r];
    size_t row = (size_t)(b * S_ + qt * 64 + wave * 16 + quad * 4 + r);
#pragma unroll
    for (int dc = 0; dc < 8; ++dc)
      attn_out[row * D_ + h * HD_ + dc * 16 + l16] = f2bf(o[dc][r] * inv);
  }
}

// ---------------- launch ----------------
extern "C" void kernel_launch(void* const* d_in, const int* in_sizes, int n_in,
                              void* d_out, int out_size, void* d_ws, size_t ws_size,
                              hipStream_t stream) {
  const float* x = (const float*)d_in[0];        // (2,2048,2048)
  const float* w_qkv = (const float*)d_in[1];    // (6144,2048)
  const float* w_out = (const float*)d_in[2];    // (2048,2048)
  const float* fcos = (const float*)d_in[3];     // (2048,64)
  const float* fsin = (const float*)d_in[4];     // (2048,64)
  float* out = (float*)d_out;                    // (2,2048,2048) fp32

  // workspace layout (bytes), total 112 MB
  char* ws = (char*)d_ws;
  ushort_t* x_bf   = (ushort_t*)(ws + 0);          // 16,777,216
  ushort_t* wqkv_bf = (ushort_t*)(ws + 16777216);  // 25,165,824
  ushort_t* wout_bf = (ushort_t*)(ws + 41943040);  // 8,388,608
  ushort_t* qkv    = (ushort_t*)(ws + 50331648);   // 50,331,648
  ushort_t* attn   = (ushort_t*)(ws + 100663296);  // 16,777,216

  cvt_f32_bf16<<<8192, 256, 0, stream>>>(x, x_bf, 2097152);
  cvt_f32_bf16<<<12288, 256, 0, stream>>>(w_qkv, wqkv_bf, 3145728);
  cvt_f32_bf16<<<4096, 256, 0, stream>>>(w_out, wout_bf, 1048576);

  // qkv = x @ w_qkv^T : M=4096, N=6144, K=2048
  gemm_bt<ushort_t><<<dim3(48, 32), 256, 0, stream>>>(x_bf, wqkv_bf, qkv,
                                                      4096, 6144, 2048);
  // RoPE on q,k in place: 4096 rows * 16 heads * 64 pairs
  rope_k<<<16384, 256, 0, stream>>>(qkv, fcos, fsin);

  // attention: grid (32 q-tiles, 16 heads, 2 batches)
  attn_fwd<<<dim3(32, 16, 2), 256, 0, stream>>>(qkv, attn);

  // out = attn @ w_out^T : M=4096, N=2048, K=2048, fp32 out
  gemm_bt<float><<<dim3(16, 32), 256, 0, stream>>>(attn, wout_bf, out,
                                                   4096, 2048, 2048);
}

// Round 2
// 552.579 us; speedup vs baseline: 1.2193x; 1.2193x over previous
//
#include <hip/hip_runtime.h>
#include <hip/hip_bf16.h>
#include <stdint.h>

// Problem: B=2, S=2048, D=2048, H=16, HD=128
#define S_ 2048
#define D_ 2048
#define H_ 16
#define HD_ 128

typedef __bf16 bf16x8 __attribute__((ext_vector_type(8)));
typedef float f32x4 __attribute__((ext_vector_type(4)));
typedef unsigned short ushort_t;
typedef ushort_t us4 __attribute__((ext_vector_type(4)));

__device__ __forceinline__ float bf2f(ushort_t u) {
  union { float f; uint32_t i; } x; x.i = ((uint32_t)u) << 16; return x.f;
}
__device__ __forceinline__ ushort_t f2bf(float f) {
  union { float f; uint32_t i; } x; x.f = f;
  uint32_t r = x.i + 0x7fffu + ((x.i >> 16) & 1u);  // RNE
  return (ushort_t)(r >> 16);
}

// async global->LDS, 16B per lane. LDS dest is wave-uniform base + lane*16.
__device__ __forceinline__ void async_copy16(const void* g, void* l) {
  __builtin_amdgcn_global_load_lds(
      (const __attribute__((address_space(1))) unsigned int*)g,
      (__attribute__((address_space(3))) unsigned int*)l, 16, 0, 0);
}

__device__ __forceinline__ void store_val(float* p, float v) { *p = v; }
__device__ __forceinline__ void store_val(ushort_t* p, float v) { *p = f2bf(v); }

// ---------------- fp32 -> bf16 convert (vectorized x4) ----------------
__global__ __launch_bounds__(256) void cvt_f32_bf16(const float* __restrict__ in,
                                                    ushort_t* __restrict__ out,
                                                    int n4) {
  int i = blockIdx.x * 256 + threadIdx.x;
  if (i >= n4) return;
  const float4 v = ((const float4*)in)[i];
  us4 o;
  o.x = f2bf(v.x); o.y = f2bf(v.y); o.z = f2bf(v.z); o.w = f2bf(v.w);
  ((us4*)out)[i] = o;
}

// ---------------- GEMM: C[M,N] = A[M,K] * B[N,K]^T  (both bf16, fp32 acc) ----
// m97 structure: 128x128 tile, BK=32, 4 waves in 2x2, global_load_lds width=16.
template <typename OutT>
__global__ __launch_bounds__(256) void gemm_bt(const ushort_t* __restrict__ A,
                                               const ushort_t* __restrict__ Bm,
                                               OutT* __restrict__ C,
                                               int M, int N, int K) {
  __shared__ __align__(16) ushort_t As[128 * 32];
  __shared__ __align__(16) ushort_t Bs[128 * 32];
  const int tid = threadIdx.x;
  const int wave = tid >> 6, lane = tid & 63;
  const int quad = lane >> 4, l16 = lane & 15;
  const int bm = blockIdx.y * 128, bn = blockIdx.x * 128;
  const int wm = (wave >> 1) * 64, wn = (wave & 1) * 64;

  f32x4 acc[4][4] = {};

  const int c0 = wave * 2, c1 = c0 + 1;
  const int srow = lane >> 2;
  const int scol = (lane & 3) * 8;
  const ushort_t* gA0 = A + (size_t)(bm + c0 * 16 + srow) * K + scol;
  const ushort_t* gA1 = A + (size_t)(bm + c1 * 16 + srow) * K + scol;
  const ushort_t* gB0 = Bm + (size_t)(bn + c0 * 16 + srow) * K + scol;
  const ushort_t* gB1 = Bm + (size_t)(bn + c1 * 16 + srow) * K + scol;
  ushort_t* lA0 = As + c0 * 512;
  ushort_t* lA1 = As + c1 * 512;
  ushort_t* lB0 = Bs + c0 * 512;
  ushort_t* lB1 = Bs + c1 * 512;

  for (int k0 = 0; k0 < K; k0 += 32) {
    __syncthreads();
    async_copy16(gA0 + k0, lA0);
    async_copy16(gA1 + k0, lA1);
    async_copy16(gB0 + k0, lB0);
    async_copy16(gB1 + k0, lB1);
    __syncthreads();
    bf16x8 af[4], bfr[4];
#pragma unroll
    for (int i = 0; i < 4; ++i)
      af[i] = *(const bf16x8*)(As + (wm + i * 16 + l16) * 32 + quad * 8);
#pragma unroll
    for (int i = 0; i < 4; ++i)
      bfr[i] = *(const bf16x8*)(Bs + (wn + i * 16 + l16) * 32 + quad * 8);
#pragma unroll
    for (int mi = 0; mi < 4; ++mi)
#pragma unroll
      for (int ni = 0; ni < 4; ++ni)
        acc[mi][ni] = __builtin_amdgcn_mfma_f32_16x16x32_bf16(af[mi], bfr[ni],
                                                              acc[mi][ni], 0, 0, 0);
  }
#pragma unroll
  for (int mi = 0; mi < 4; ++mi)
#pragma unroll
    for (int ni = 0; ni < 4; ++ni)
#pragma unroll
      for (int r = 0; r < 4; ++r) {
        int row = bm + wm + mi * 16 + quad * 4 + r;
        int col = bn + wn + ni * 16 + l16;
        store_val(&C[(size_t)row * N + col], acc[mi][ni][r]);
      }
}

// ---------------- RoPE in-place on q and k halves of qkv ----------------
__global__ __launch_bounds__(256) void rope_k(ushort_t* __restrict__ qkv,
                                              const float* __restrict__ fc,
                                              const float* __restrict__ fs) {
  int idx = blockIdx.x * 256 + threadIdx.x;
  int i = idx & 63;
  int hh = (idx >> 6) & 15;
  int m = idx >> 10;
  int s = m & (S_ - 1);
  float c = fc[s * 64 + i], sn = fs[s * 64 + i];
  size_t off = (size_t)m * (3 * D_) + hh * HD_ + 2 * i;
#pragma unroll
  for (int part = 0; part < 2; ++part) {
    uint32_t* p = (uint32_t*)(qkv + off + part * D_);
    uint32_t v = *p;
    float re = bf2f((ushort_t)(v & 0xffffu));
    float im = bf2f((ushort_t)(v >> 16));
    float nr = re * c - im * sn;
    float ni = re * sn + im * c;
    *p = (uint32_t)f2bf(nr) | ((uint32_t)f2bf(ni) << 16);
  }
}

// ---------------- Flash attention v2 (causal, fixed-max softmax) -------------
// grid: (qt=S/64, H, B) with qt reversed; block 256 (4 waves, 16 q-rows each)
// Bk=64 key tile, register-prefetch double buffering, padded LDS strides.
#define KL_STRIDE 136   // 64 rows x (128 + 8 pad)
#define VT_STRIDE 76    // 128 rows(d) x (64 + 12 pad)
#define P_STRIDE  72    // 16 rows(q) x (64 + 8 pad)
#define SOFTMAX_C 12.0f

__global__ __launch_bounds__(256, 3) void attn_fwd(const ushort_t* __restrict__ qkv,
                                                   ushort_t* __restrict__ attn_out) {
  const int qt = (int)gridDim.x - 1 - (int)blockIdx.x;  // longest blocks first
  const int h = blockIdx.y, b = blockIdx.z;
  __shared__ __align__(16) ushort_t Kl[64 * KL_STRIDE];   // 17408 B
  __shared__ __align__(16) ushort_t VT[128 * VT_STRIDE];  // 19456 B
  __shared__ __align__(16) ushort_t Pl[4 * 16 * P_STRIDE];// 9216 B

  const int tid = threadIdx.x;
  const int wave = tid >> 6, lane = tid & 63;
  const int quad = lane >> 4, l16 = lane & 15;
  const float scale = 0.08838834764831845f;  // 1/sqrt(128)

  // Q fragments (A layout: m=lane&15, k=quad*8+j)
  const int qg = qt * 64 + wave * 16 + l16;
  const ushort_t* qrow = qkv + (size_t)(b * S_ + qg) * (3 * D_) + h * HD_;
  bf16x8 qf[4];
#pragma unroll
  for (int c = 0; c < 4; ++c)
    qf[c] = *(const bf16x8*)(qrow + c * 32 + quad * 8);

  f32x4 o[8] = {};
  float lsum[4] = {0.f, 0.f, 0.f, 0.f};
  const int q_row_base = qt * 64 + wave * 16 + quad * 4;  // C-layout rows
  ushort_t* Pw = Pl + wave * 16 * P_STRIDE;

  // staging coords
  const int kr = tid >> 2;            // K stage: row 0..63
  const int kc = (tid & 3) * 32;      //          col chunk (32 shorts)
  const int vkq = tid & 15;           // V stage: key quad (4 keys)
  const int vdg = tid >> 4;           //          d group (8 d)
  const ushort_t* gK = qkv + (size_t)(b * S_) * (3 * D_) + D_ + h * HD_;
  const ushort_t* gV = qkv + (size_t)(b * S_) * (3 * D_) + 2 * D_ + h * HD_;

  uint4 pk[4], pv[4];
#define PREFETCH(KT)                                                        \
  {                                                                         \
    const ushort_t* pkg = gK + (size_t)((KT) * 64 + kr) * (3 * D_) + kc;    \
    pk[0] = *(const uint4*)(pkg);                                           \
    pk[1] = *(const uint4*)(pkg + 8);                                       \
    pk[2] = *(const uint4*)(pkg + 16);                                      \
    pk[3] = *(const uint4*)(pkg + 24);                                      \
    const ushort_t* pvg = gV + (size_t)((KT) * 64 + vkq * 4) * (3 * D_) + vdg * 8; \
    pv[0] = *(const uint4*)(pvg);                                           \
    pv[1] = *(const uint4*)(pvg + 3 * D_);                                  \
    pv[2] = *(const uint4*)(pvg + 6 * D_);                                  \
    pv[3] = *(const uint4*)(pvg + 9 * D_);                                  \
  }

  PREFETCH(0)
  for (int kt = 0; kt <= qt; ++kt) {
    __syncthreads();  // previous compute done reading LDS
    // commit prefetched K tile
    {
      ushort_t* lk = Kl + kr * KL_STRIDE + kc;
      *(uint4*)(lk) = pk[0];
      *(uint4*)(lk + 8) = pk[1];
      *(uint4*)(lk + 16) = pk[2];
      *(uint4*)(lk + 24) = pk[3];
      // commit V transposed: b64 writes (4 keys packed per d)
      ushort_t va[4][8];
      *(uint4*)va[0] = pv[0]; *(uint4*)va[1] = pv[1];
      *(uint4*)va[2] = pv[2]; *(uint4*)va[3] = pv[3];
#pragma unroll
      for (int j = 0; j < 8; ++j) {
        us4 w = {va[0][j], va[1][j], va[2][j], va[3][j]};
        *(us4*)(VT + (vdg * 8 + j) * VT_STRIDE + vkq * 4) = w;
      }
    }
    if (kt < qt) PREFETCH(kt + 1)  // global loads overlap compute below
    __syncthreads();

    // QK^T: 4 key groups of 16, K=128 over 4 MFMA each
    const int qlim = (kt == qt) ? q_row_base : (1 << 30);
#pragma unroll
    for (int g = 0; g < 4; ++g) {
      f32x4 s = {0.f, 0.f, 0.f, 0.f};
#pragma unroll
      for (int c = 0; c < 4; ++c) {
        bf16x8 kf = *(const bf16x8*)(Kl + (g * 16 + l16) * KL_STRIDE + c * 32 + quad * 8);
        s = __builtin_amdgcn_mfma_f32_16x16x32_bf16(qf[c], kf, s, 0, 0, 0);
      }
      const int key = kt * 64 + g * 16 + l16;
#pragma unroll
      for (int r = 0; r < 4; ++r) {
        float e = __expf(s[r] * scale - SOFTMAX_C);
        float p = (key <= qlim + r) ? e : 0.f;
        lsum[r] += p;
        Pw[(quad * 4 + r) * P_STRIDE + g * 16 + l16] = f2bf(p);
      }
    }
    // P (C layout) -> per-wave LDS -> A layout (no barrier: wave-private)
    bf16x8 pf0 = *(const bf16x8*)(Pw + l16 * P_STRIDE + quad * 8);
    bf16x8 pf1 = *(const bf16x8*)(Pw + l16 * P_STRIDE + 32 + quad * 8);
#pragma unroll
    for (int dc = 0; dc < 8; ++dc) {
      bf16x8 v0 = *(const bf16x8*)(VT + (dc * 16 + l16) * VT_STRIDE + quad * 8);
      o[dc] = __builtin_amdgcn_mfma_f32_16x16x32_bf16(pf0, v0, o[dc], 0, 0, 0);
      bf16x8 v1 = *(const bf16x8*)(VT + (dc * 16 + l16) * VT_STRIDE + 32 + quad * 8);
      o[dc] = __builtin_amdgcn_mfma_f32_16x16x32_bf16(pf1, v1, o[dc], 0, 0, 0);
    }
  }
#undef PREFETCH

  // epilogue: reduce row sums across 16 lanes, normalize, store bf16
#pragma unroll
  for (int r = 0; r < 4; ++r) {
    float l = lsum[r];
    l += __shfl_xor(l, 1, 64);
    l += __shfl_xor(l, 2, 64);
    l += __shfl_xor(l, 4, 64);
    l += __shfl_xor(l, 8, 64);
    float inv = 1.0f / l;
    size_t row = (size_t)(b * S_ + q_row_base + r);
#pragma unroll
    for (int dc = 0; dc < 8; ++dc)
      attn_out[row * D_ + h * HD_ + dc * 16 + l16] = f2bf(o[dc][r] * inv);
  }
}

// ---------------- launch ----------------
extern "C" void kernel_launch(void* const* d_in, const int* in_sizes, int n_in,
                              void* d_out, int out_size, void* d_ws, size_t ws_size,
                              hipStream_t stream) {
  const float* x = (const float*)d_in[0];
  const float* w_qkv = (const float*)d_in[1];
  const float* w_out = (const float*)d_in[2];
  const float* fcos = (const float*)d_in[3];
  const float* fsin = (const float*)d_in[4];
  float* out = (float*)d_out;

  char* ws = (char*)d_ws;
  ushort_t* x_bf    = (ushort_t*)(ws + 0);
  ushort_t* wqkv_bf = (ushort_t*)(ws + 16777216);
  ushort_t* wout_bf = (ushort_t*)(ws + 41943040);
  ushort_t* qkv     = (ushort_t*)(ws + 50331648);
  ushort_t* attn    = (ushort_t*)(ws + 100663296);

  cvt_f32_bf16<<<8192, 256, 0, stream>>>(x, x_bf, 2097152);
  cvt_f32_bf16<<<12288, 256, 0, stream>>>(w_qkv, wqkv_bf, 3145728);
  cvt_f32_bf16<<<4096, 256, 0, stream>>>(w_out, wout_bf, 1048576);

  // qkv = x @ w_qkv^T : M=4096, N=6144, K=2048
  gemm_bt<ushort_t><<<dim3(48, 32), 256, 0, stream>>>(x_bf, wqkv_bf, qkv,
                                                      4096, 6144, 2048);
  rope_k<<<16384, 256, 0, stream>>>(qkv, fcos, fsin);

  attn_fwd<<<dim3(32, 16, 2), 256, 0, stream>>>(qkv, attn);

  // out = attn @ w_out^T : M=4096, N=2048, K=2048, fp32 out
  gemm_bt<float><<<dim3(16, 32), 256, 0, stream>>>(attn, wout_bf, out,
                                                   4096, 2048, 2048);
}

// Round 3
// 461.684 us; speedup vs baseline: 1.4594x; 1.1969x over previous
//
#include <hip/hip_runtime.h>
#include <hip/hip_bf16.h>
#include <stdint.h>

// Problem: B=2, S=2048, D=2048, H=16, HD=128
#define S_ 2048
#define D_ 2048
#define H_ 16
#define HD_ 128

typedef __bf16 bf16x8 __attribute__((ext_vector_type(8)));
typedef float f32x4 __attribute__((ext_vector_type(4)));
typedef unsigned short ushort_t;
typedef ushort_t us4 __attribute__((ext_vector_type(4)));

__device__ __forceinline__ float bf2f(ushort_t u) {
  union { float f; uint32_t i; } x; x.i = ((uint32_t)u) << 16; return x.f;
}
__device__ __forceinline__ ushort_t f2bf(float f) {
  union { float f; uint32_t i; } x; x.f = f;
  uint32_t r = x.i + 0x7fffu + ((x.i >> 16) & 1u);  // RNE
  return (ushort_t)(r >> 16);
}

// async global->LDS, 16B per lane. LDS dest is wave-uniform base + lane*16.
__device__ __forceinline__ void async_copy16(const void* g, void* l) {
  __builtin_amdgcn_global_load_lds(
      (const __attribute__((address_space(1))) unsigned int*)g,
      (__attribute__((address_space(3))) unsigned int*)l, 16, 0, 0);
}

__device__ __forceinline__ void store_val(float* p, float v) { *p = v; }
__device__ __forceinline__ void store_val(ushort_t* p, float v) { *p = f2bf(v); }

// ---------------- fp32 -> bf16 convert (vectorized x4) ----------------
__global__ __launch_bounds__(256) void cvt_f32_bf16(const float* __restrict__ in,
                                                    ushort_t* __restrict__ out,
                                                    int n4) {
  int i = blockIdx.x * 256 + threadIdx.x;
  if (i >= n4) return;
  const float4 v = ((const float4*)in)[i];
  us4 o;
  o.x = f2bf(v.x); o.y = f2bf(v.y); o.z = f2bf(v.z); o.w = f2bf(v.w);
  ((us4*)out)[i] = o;
}

// ---------------- GEMM: C[M,N] = A[M,K] * B[N,K]^T  (bf16, fp32 acc) --------
template <typename OutT>
__global__ __launch_bounds__(256) void gemm_bt(const ushort_t* __restrict__ A,
                                               const ushort_t* __restrict__ Bm,
                                               OutT* __restrict__ C,
                                               int M, int N, int K) {
  __shared__ __align__(16) ushort_t As[128 * 32];
  __shared__ __align__(16) ushort_t Bs[128 * 32];
  const int tid = threadIdx.x;
  const int wave = tid >> 6, lane = tid & 63;
  const int quad = lane >> 4, l16 = lane & 15;
  const int bm = blockIdx.y * 128, bn = blockIdx.x * 128;
  const int wm = (wave >> 1) * 64, wn = (wave & 1) * 64;

  f32x4 acc[4][4] = {};

  const int c0 = wave * 2, c1 = c0 + 1;
  const int srow = lane >> 2;
  const int scol = (lane & 3) * 8;
  const ushort_t* gA0 = A + (size_t)(bm + c0 * 16 + srow) * K + scol;
  const ushort_t* gA1 = A + (size_t)(bm + c1 * 16 + srow) * K + scol;
  const ushort_t* gB0 = Bm + (size_t)(bn + c0 * 16 + srow) * K + scol;
  const ushort_t* gB1 = Bm + (size_t)(bn + c1 * 16 + srow) * K + scol;
  ushort_t* lA0 = As + c0 * 512;
  ushort_t* lA1 = As + c1 * 512;
  ushort_t* lB0 = Bs + c0 * 512;
  ushort_t* lB1 = Bs + c1 * 512;

  for (int k0 = 0; k0 < K; k0 += 32) {
    __syncthreads();
    async_copy16(gA0 + k0, lA0);
    async_copy16(gA1 + k0, lA1);
    async_copy16(gB0 + k0, lB0);
    async_copy16(gB1 + k0, lB1);
    __syncthreads();
    bf16x8 af[4], bfr[4];
#pragma unroll
    for (int i = 0; i < 4; ++i)
      af[i] = *(const bf16x8*)(As + (wm + i * 16 + l16) * 32 + quad * 8);
#pragma unroll
    for (int i = 0; i < 4; ++i)
      bfr[i] = *(const bf16x8*)(Bs + (wn + i * 16 + l16) * 32 + quad * 8);
#pragma unroll
    for (int mi = 0; mi < 4; ++mi)
#pragma unroll
      for (int ni = 0; ni < 4; ++ni)
        acc[mi][ni] = __builtin_amdgcn_mfma_f32_16x16x32_bf16(af[mi], bfr[ni],
                                                              acc[mi][ni], 0, 0, 0);
  }
#pragma unroll
  for (int mi = 0; mi < 4; ++mi)
#pragma unroll
    for (int ni = 0; ni < 4; ++ni)
#pragma unroll
      for (int r = 0; r < 4; ++r) {
        int row = bm + wm + mi * 16 + quad * 4 + r;
        int col = bn + wn + ni * 16 + l16;
        store_val(&C[(size_t)row * N + col], acc[mi][ni][r]);
      }
}

// ---------------- RoPE in-place on q and k halves of qkv ----------------
__global__ __launch_bounds__(256) void rope_k(ushort_t* __restrict__ qkv,
                                              const float* __restrict__ fc,
                                              const float* __restrict__ fs) {
  int idx = blockIdx.x * 256 + threadIdx.x;
  int i = idx & 63;
  int hh = (idx >> 6) & 15;
  int m = idx >> 10;
  int s = m & (S_ - 1);
  float c = fc[s * 64 + i], sn = fs[s * 64 + i];
  size_t off = (size_t)m * (3 * D_) + hh * HD_ + 2 * i;
#pragma unroll
  for (int part = 0; part < 2; ++part) {
    uint32_t* p = (uint32_t*)(qkv + off + part * D_);
    uint32_t v = *p;
    float re = bf2f((ushort_t)(v & 0xffffu));
    float im = bf2f((ushort_t)(v >> 16));
    float nr = re * c - im * sn;
    float ni = re * sn + im * c;
    *p = (uint32_t)f2bf(nr) | ((uint32_t)f2bf(ni) << 16);
  }
}

// ---------------- V transpose: qkv V part -> VTg[(b*H+h)*HD + d][S] ---------
// grid (S/64, H, B), block 256
__global__ __launch_bounds__(256) void vt_prep(const ushort_t* __restrict__ qkv,
                                               ushort_t* __restrict__ VTg) {
  __shared__ __align__(16) ushort_t T[64 * 136];
  const int st = blockIdx.x, h = blockIdx.y, b = blockIdx.z;
  const int tid = threadIdx.x;
  const ushort_t* gV = qkv + (size_t)(b * S_ + st * 64) * (3 * D_) + 2 * D_ + h * HD_;
  {
    const int r = tid >> 2, cc = (tid & 3) * 32;
    const ushort_t* src = gV + (size_t)r * (3 * D_) + cc;
    uint4 a0 = ((const uint4*)src)[0];
    uint4 a1 = ((const uint4*)src)[1];
    uint4 a2 = ((const uint4*)src)[2];
    uint4 a3 = ((const uint4*)src)[3];
    ushort_t* dst = T + r * 136 + cc;
    ((uint4*)dst)[0] = a0; ((uint4*)dst)[1] = a1;
    ((uint4*)dst)[2] = a2; ((uint4*)dst)[3] = a3;
  }
  __syncthreads();
  const int d = tid >> 1, kh = (tid & 1) * 32;
  ushort_t buf[32];
#pragma unroll
  for (int j = 0; j < 32; ++j) buf[j] = T[(kh + j) * 136 + d];
  ushort_t* out = VTg + ((size_t)((b * H_ + h) * HD_ + d)) * S_ + st * 64 + kh;
  ((uint4*)out)[0] = *(const uint4*)(buf + 0);
  ((uint4*)out)[1] = *(const uint4*)(buf + 8);
  ((uint4*)out)[2] = *(const uint4*)(buf + 16);
  ((uint4*)out)[3] = *(const uint4*)(buf + 24);
}

// ---------------- Flash attention v3: key-split chunks, async staging -------
// grid.x = 80 chunk slots per (h,b): qt 0-7 ->1 chunk, 8-15 ->2, 16-23 ->3,
// 24-31 ->4 (chunk = 8 key tiles of 64). Partials accumulate via fp32 atomics.
#define SOFTMAX_C 12.0f

__global__ __launch_bounds__(256, 4) void attn_fwd(const ushort_t* __restrict__ qkv,
                                                   const ushort_t* __restrict__ VTg,
                                                   float* __restrict__ Oacc,
                                                   float* __restrict__ lsum_g) {
  // swizzled LDS, no padding (phys_chunk = chunk ^ (row & mask)); 40960 B total
  __shared__ __align__(16) ushort_t Kl[64 * 128];   // [key][d]   16 KB
  __shared__ __align__(16) ushort_t VT[128 * 64];   // [d][key]   16 KB
  __shared__ __align__(16) ushort_t Pl[4 * 16 * 64];// per-wave P  8 KB

  // decode chunk slot -> (qt, c); reverse so full chunks dispatch first
  const int j = 79 - (int)blockIdx.x;
  int qt, c;
  if (j < 8)       { qt = j;                 c = 0; }
  else if (j < 24) { int t = j - 8;  qt = 8 + (t >> 1);  c = t & 1; }
  else if (j < 48) { int t = j - 24; qt = 16 + t / 3;    c = t % 3; }
  else             { int t = j - 48; qt = 24 + (t >> 2); c = t & 3; }
  const int h = blockIdx.y, b = blockIdx.z;
  const int kt0 = c * 8;
  const int kt_end = min(kt0 + 8, qt + 1);

  const int tid = threadIdx.x;
  const int wave = tid >> 6, lane = tid & 63;
  const int quad = lane >> 4, l16 = lane & 15;
  const float scale = 0.08838834764831845f;  // 1/sqrt(128)

  // Q fragments (A layout: m=lane&15, k=quad*8+j)
  const int qg = qt * 64 + wave * 16 + l16;
  const ushort_t* qrow = qkv + (size_t)(b * S_ + qg) * (3 * D_) + h * HD_;
  bf16x8 qf[4];
#pragma unroll
  for (int cc = 0; cc < 4; ++cc)
    qf[cc] = *(const bf16x8*)(qrow + cc * 32 + quad * 8);

  f32x4 o[8] = {};
  float lsum[4] = {0.f, 0.f, 0.f, 0.f};
  const int q_row_base = qt * 64 + wave * 16 + quad * 4;
  ushort_t* Pw = Pl + wave * 16 * 64;

  const ushort_t* gK = qkv + (size_t)(b * S_) * (3 * D_) + D_ + h * HD_;
  const ushort_t* gVT = VTg + (size_t)(b * H_ + h) * HD_ * S_;

  // staging lane coords
  const int krow_off = lane >> 4;            // K: +row within 4-row group
  const int kchunk = lane & 15;              // K: phys 16B chunk (of 16)
  const int vrow_off = lane >> 3;            // V: +row within 8-row group
  const int vchunk = lane & 7;               // V: phys 16B chunk (of 8)

  for (int kt = kt0; kt < kt_end; ++kt) {
    __syncthreads();  // all waves done reading Kl/VT
    // K tile: 64 rows x 256 B, swizzle phys = chunk ^ (row&15)
#pragma unroll
    for (int i = 0; i < 4; ++i) {
      int row = wave * 16 + i * 4 + krow_off;
      int lchunk = kchunk ^ (row & 15);
      async_copy16(gK + (size_t)(kt * 64 + row) * (3 * D_) + lchunk * 8,
                   Kl + (wave * 16 + i * 4) * 128);
    }
    // V^T tile: 128 d-rows x 128 B, swizzle phys = chunk ^ (row&7)
#pragma unroll
    for (int i = 0; i < 4; ++i) {
      int row = wave * 32 + i * 8 + vrow_off;
      int lchunk = vchunk ^ (row & 7);
      async_copy16(gVT + (size_t)row * S_ + kt * 64 + lchunk * 8,
                   VT + (wave * 32 + i * 8) * 64);
    }
    __syncthreads();  // drains vmcnt -> LDS ready

    const bool diag = (kt == qt);
    // QK^T: 4 key groups of 16, K=128 over 4 MFMA each
#pragma unroll
    for (int g = 0; g < 4; ++g) {
      f32x4 s = {0.f, 0.f, 0.f, 0.f};
#pragma unroll
      for (int cc = 0; cc < 4; ++cc) {
        bf16x8 kf = *(const bf16x8*)(Kl + (g * 16 + l16) * 128 +
                                     (((cc * 4 + quad) ^ l16) * 8));
        s = __builtin_amdgcn_mfma_f32_16x16x32_bf16(qf[cc], kf, s, 0, 0, 0);
      }
      const int key = kt * 64 + g * 16 + l16;
#pragma unroll
      for (int r = 0; r < 4; ++r) {
        float e = __expf(s[r] * scale - SOFTMAX_C);
        float p = (!diag || key <= q_row_base + r) ? e : 0.f;
        lsum[r] += p;
        int prow = quad * 4 + r;
        int pcol = g * 16 + l16;
        Pw[prow * 64 + (((pcol >> 3) ^ (prow & 7)) * 8) + (pcol & 7)] = f2bf(p);
      }
    }
    // P reload in A layout (wave-private, no barrier)
    bf16x8 pf0 = *(const bf16x8*)(Pw + l16 * 64 + ((quad ^ (l16 & 7)) * 8));
    bf16x8 pf1 = *(const bf16x8*)(Pw + l16 * 64 + (((4 + quad) ^ (l16 & 7)) * 8));
#pragma unroll
    for (int dc = 0; dc < 8; ++dc) {
      bf16x8 v0 = *(const bf16x8*)(VT + (dc * 16 + l16) * 64 +
                                   (((0 * 4 + quad) ^ (l16 & 7)) * 8));
      o[dc] = __builtin_amdgcn_mfma_f32_16x16x32_bf16(pf0, v0, o[dc], 0, 0, 0);
      bf16x8 v1 = *(const bf16x8*)(VT + (dc * 16 + l16) * 64 +
                                   (((1 * 4 + quad) ^ (l16 & 7)) * 8));
      o[dc] = __builtin_amdgcn_mfma_f32_16x16x32_bf16(pf1, v1, o[dc], 0, 0, 0);
    }
  }

  // accumulate partials: O via fp32 atomics, lsum via one atomic per row
#pragma unroll
  for (int r = 0; r < 4; ++r) {
    float l = lsum[r];
    l += __shfl_xor(l, 1, 64);
    l += __shfl_xor(l, 2, 64);
    l += __shfl_xor(l, 4, 64);
    l += __shfl_xor(l, 8, 64);
    size_t row = (size_t)(b * S_ + q_row_base + r);
    if (l16 == 0) unsafeAtomicAdd(&lsum_g[row * H_ + h], l);
#pragma unroll
    for (int dc = 0; dc < 8; ++dc)
      unsafeAtomicAdd(&Oacc[row * D_ + h * HD_ + dc * 16 + l16], o[dc][r]);
  }
}

// ---------------- combine: normalize O by lsum, emit bf16 -------------------
__global__ __launch_bounds__(256) void combine(const float* __restrict__ Oacc,
                                               const float* __restrict__ lsum_g,
                                               ushort_t* __restrict__ attn) {
  int i = blockIdx.x * 256 + threadIdx.x;  // one float4 per thread
  float4 v = ((const float4*)Oacc)[i];
  int flat = i * 4;
  int row = flat >> 11;          // / D_
  int h = (flat >> 7) & 15;      // (flat % D_) / HD_
  float inv = 1.0f / lsum_g[row * H_ + h];
  us4 o;
  o.x = f2bf(v.x * inv); o.y = f2bf(v.y * inv);
  o.z = f2bf(v.z * inv); o.w = f2bf(v.w * inv);
  ((us4*)attn)[i] = o;
}

// ---------------- launch ----------------
extern "C" void kernel_launch(void* const* d_in, const int* in_sizes, int n_in,
                              void* d_out, int out_size, void* d_ws, size_t ws_size,
                              hipStream_t stream) {
  const float* x = (const float*)d_in[0];
  const float* w_qkv = (const float*)d_in[1];
  const float* w_out = (const float*)d_in[2];
  const float* fcos = (const float*)d_in[3];
  const float* fsin = (const float*)d_in[4];
  float* out = (float*)d_out;

  char* ws = (char*)d_ws;
  // phase-1 layout
  ushort_t* x_bf    = (ushort_t*)(ws + 0);          // dead after gemm1
  ushort_t* wqkv_bf = (ushort_t*)(ws + 16777216);   // dead after gemm1
  ushort_t* wout_bf = (ushort_t*)(ws + 41943040);   // live till gemm2
  ushort_t* qkv     = (ushort_t*)(ws + 50331648);   // live till attn
  ushort_t* attn    = (ushort_t*)(ws + 100663296);  // written by combine
  // phase-2 aliases
  float* Oacc   = (float*)(ws + 0);          // 33.5 MB over x_bf+wqkv_bf
  float* lsum_g = (float*)(ws + 33554432);   // 256 KB, still in wqkv_bf region
  ushort_t* VTg = (ushort_t*)(ws + 100663296); // aliases attn (disjoint lifetime)

  cvt_f32_bf16<<<8192, 256, 0, stream>>>(x, x_bf, 2097152);
  cvt_f32_bf16<<<12288, 256, 0, stream>>>(w_qkv, wqkv_bf, 3145728);
  cvt_f32_bf16<<<4096, 256, 0, stream>>>(w_out, wout_bf, 1048576);

  // qkv = x @ w_qkv^T : M=4096, N=6144, K=2048
  gemm_bt<ushort_t><<<dim3(48, 32), 256, 0, stream>>>(x_bf, wqkv_bf, qkv,
                                                      4096, 6144, 2048);
  rope_k<<<16384, 256, 0, stream>>>(qkv, fcos, fsin);
  vt_prep<<<dim3(32, 16, 2), 256, 0, stream>>>(qkv, VTg);

  // zero accumulators (x_bf/wqkv_bf are dead now)
  hipMemsetAsync(Oacc, 0, 33554432, stream);
  hipMemsetAsync(lsum_g, 0, 262144, stream);

  attn_fwd<<<dim3(80, 16, 2), 256, 0, stream>>>(qkv, VTg, Oacc, lsum_g);
  combine<<<8192, 256, 0, stream>>>(Oacc, lsum_g, attn);

  // out = attn @ w_out^T : M=4096, N=2048, K=2048, fp32 out
  gemm_bt<float><<<dim3(16, 32), 256, 0, stream>>>(attn, wout_bf, out,
                                                   4096, 2048, 2048);
}